// Round 15
// baseline (2943.954 us; speedup 1.0000x reference)
//
#include <hip/hip_runtime.h>
#include <hip/hip_bf16.h>

#define kB 128
#define kS 1024
#define kT 512
#define kV 1000
#define kE 128
#define kHE 64
#define kHD 66
#define kATT 32
#define kGE 256   // 4*kHE
#define kGD 264   // 4*kHD

typedef __attribute__((ext_vector_type(4))) float f32x4;
typedef __attribute__((ext_vector_type(8))) short bf16x8;
typedef __attribute__((ext_vector_type(8))) unsigned short u16x8;

__device__ __forceinline__ unsigned short f2bf(float f) {
  unsigned int u = __builtin_bit_cast(unsigned int, f);
  u += 0x7FFFu + ((u >> 16) & 1u);
  return (unsigned short)(u >> 16);
}
__device__ __forceinline__ float rcp_(float x) { return __builtin_amdgcn_rcpf(x); }
__device__ __forceinline__ float fsig(float x)  { return rcp_(1.0f + __expf(-x)); }
__device__ __forceinline__ float ftanh(float x) { return 1.0f - 2.0f * rcp_(1.0f + __expf(2.0f * x)); }
__device__ __forceinline__ float fexp2(float z) {
#if __has_builtin(__builtin_amdgcn_exp2f)
  return __builtin_amdgcn_exp2f(z);
#else
  return __expf(z * 0.6931471805599453f);
#endif
}
__device__ __forceinline__ const unsigned short* launder_us(const unsigned short* p) {
  asm volatile("" : "+s"(p));
  return p;
}
// VALU-rate sum over each contiguous 16-lane row.
__device__ __forceinline__ float dpp_red16(float v) {
  int x = __builtin_bit_cast(int, v);
  v += __builtin_bit_cast(float, __builtin_amdgcn_update_dpp(0, x, 0xB1, 0xf, 0xf, true));  // quad_perm [1,0,3,2]
  x = __builtin_bit_cast(int, v);
  v += __builtin_bit_cast(float, __builtin_amdgcn_update_dpp(0, x, 0x4E, 0xf, 0xf, true));  // quad_perm [2,3,0,1]
  x = __builtin_bit_cast(int, v);
  v += __builtin_bit_cast(float, __builtin_amdgcn_update_dpp(0, x, 0x124, 0xf, 0xf, true)); // row_ror:4
  x = __builtin_bit_cast(int, v);
  v += __builtin_bit_cast(float, __builtin_amdgcn_update_dpp(0, x, 0x128, 0xf, 0xf, true)); // row_ror:8
  return v;
}
// quad_perm broadcast of quad-lane i (ctrl must be a literal)
#define DPPB(v, ctrl) __builtin_bit_cast(float, __builtin_amdgcn_update_dpp(0, __builtin_bit_cast(int, (v)), (ctrl), 0xf, 0xf, true))

// ---------------------------------------------------------------------------
// prep. Fragment layout: frag[((tile*KS + ks)*64 + lane)*8 + jj] = B[k][col],
// col = lane&15. BOTH decF and encF cols are CELL-MAJOR (j' = cell*4+gate) so
// gates->cells compute in-wave via quad DPP. embW also stored cell-major.
// ---------------------------------------------------------------------------
__global__ __launch_bounds__(256) void prep_kernel(
    const float* __restrict__ emb, const float* __restrict__ enc_Wih,
    const float* __restrict__ enc_b, const float* __restrict__ enc_Whh,
    const float* __restrict__ att_fc_W, const float* __restrict__ att_fc_b,
    const float* __restrict__ att_w_W,
    const float* __restrict__ fin_W, const float* __restrict__ fin_b,
    const float* __restrict__ dec_Wih, const float* __restrict__ dec_Whh,
    const float* __restrict__ dec_b,
    float* __restrict__ embW, unsigned short* __restrict__ decF,
    unsigned short* __restrict__ encF, unsigned short* __restrict__ afF,
    float* __restrict__ wregF, float* __restrict__ dbias,
    float* __restrict__ wh64, float* __restrict__ wh65,
    float* __restrict__ abias, float* __restrict__ ainit) {
  int bid = blockIdx.x, tid = threadIdx.x;
  if (bid < kV) {
    // tid = gate-major j; store CELL-MAJOR: jp = cell*4 + gate
    float acc = enc_b[tid];
    const float* er = emb + bid * kE;
    const float* wr = enc_Wih + tid * kE;
    for (int e = 0; e < kE; ++e) acc += er[e] * wr[e];
    embW[bid * kGE + (tid & 63) * 4 + (tid >> 6)] = acc;
  } else if (bid == kV) {
    // decF: 17 tiles x 3 ksteps, cols cell-major: j' = cell*4+gate
    for (int i = tid; i < 17 * 3 * 64 * 8; i += 256) {
      int jj = i & 7, lane = (i >> 3) & 63, ts = i >> 9;
      int tile = ts / 3, ks = ts - tile * 3;
      int jp = tile * 16 + (lane & 15);
      int cell = jp >> 2, gate = jp & 3;
      int k = ks * 32 + ((lane >> 4) << 3) + jj;
      float v = 0.f;
      if (cell < kHD) {
        int j = gate * kHD + cell;
        if (k < 32) v = dec_Wih[j * kATT + k];
        else v = dec_Whh[j * kHD + (k - 32)];
      }
      decF[i] = f2bf(v);
    }
  } else if (bid == kV + 1) {
    // encF: 16 tiles x 2 ksteps, cols cell-major (cell<64, gate<4)
    for (int i = tid; i < 16 * 2 * 64 * 8; i += 256) {
      int jj = i & 7, lane = (i >> 3) & 63, ts = i >> 9;
      int tile = ts >> 1, ks = ts & 1;
      int jp = tile * 16 + (lane & 15);
      int cell = jp >> 2, gate = jp & 3;
      int j = gate * kHE + cell;
      int k = ks * 32 + ((lane >> 4) << 3) + jj;
      encF[i] = f2bf(enc_Whh[j * kHE + k]);
    }
  } else if (bid == kV + 2) {
    for (int i = tid; i < 4 * 3 * 64 * 8; i += 256) {
      int jj = i & 7, lane = (i >> 3) & 63, ts = i >> 9;
      int tile = ts / 3, ks = ts - tile * 3;
      int aidx = tile * 16 + (lane & 15);
      int m = ks * 32 + ((lane >> 4) << 3) + jj;
      float v = 0.f;
      if (m < kHD)
        for (int e = 0; e < kE; ++e) v += att_fc_W[aidx * kE + e] * fin_W[e * kHD + m];
      afF[i] = f2bf(v);
    }
  } else if (bid == kV + 3) {
    for (int i = tid; i < 8 * 64 * 4; i += 256) {
      int c = i & 3, lane = (i >> 2) & 63, jq = i >> 8;
      int half = jq & 1, kc = (jq >> 1) & 1, mt = jq >> 2;
      wregF[i] = att_w_W[(mt * 16 + (lane & 15)) * kHE + kc * 32 + ((lane >> 4) << 3) + half * 4 + c];
    }
  } else if (bid == kV + 4) {
    // permuted bias / rank-2 fixup arrays: index jp = cell*4+gate
    for (int jp = tid; jp < kGD; jp += 256) {
      int cell = jp >> 2, gate = jp & 3;
      int j = gate * kHD + cell;
      float s = 0.f;
      for (int m = 0; m < kATT; ++m) s += dec_Wih[j * kATT + m];
      dbias[jp] = dec_b[j] + 32.0f * s;
      wh64[jp] = dec_Whh[j * kHD + 64];
      wh65[jp] = dec_Whh[j * kHD + 65];
    }
  } else {
    if (tid < kHE) {
      float acc = att_fc_b[tid];
      for (int e = 0; e < kE; ++e) acc += att_fc_W[tid * kE + e] * fin_b[e];
      abias[tid] = acc;
    } else if (tid < 2 * kHE) {
      int a = tid - kHE;
      float acc = att_fc_b[a];
      for (int e = 0; e < kE; ++e) acc += emb[e] * att_fc_W[a * kE + e];
      ainit[a] = acc;
    }
  }
}

// ---------------------------------------------------------------------------
// encoder: 1 block/b, 256 thr, ONE barrier per step (was 2).
// Cell-major encF: each 16x16 tile yields 4 gates x 4 cells -> in-wave LSTM
// via quad DPP broadcasts (validated dec-P2 pattern). gbuf eliminated; all
// 256 threads active in the cell phase; xe double-buffered by step parity.
// ---------------------------------------------------------------------------
__global__ __launch_bounds__(256)
__attribute__((amdgpu_waves_per_eu(1, 1)))
void enc_kernel(
    const int* __restrict__ x, const float* __restrict__ embW,
    const unsigned short* __restrict__ encF, float* __restrict__ out) {
  __shared__ struct __align__(16) {
    unsigned short xe[2][64];
    int toks[kS];
  } sm;
  const int b = blockIdx.x, t = threadIdx.x, lane = t & 63, wv = t >> 6;
  const int lr = lane & 15;
  const int gate = lane & 3;
  const float kk = (gate == 2) ? 2.0f : 1.0f;

  for (int i = t; i < kS; i += 256) sm.toks[i] = x[b * kS + i];
  if (t < 128) ((unsigned short*)sm.xe)[t] = 0;

  u16x8 eQ[4][2];
  #pragma unroll
  for (int q = 0; q < 4; ++q)
    #pragma unroll
    for (int ks = 0; ks < 2; ++ks)
      eQ[q][ks] = *(const u16x8*)&encF[(((wv * 4 + q) * 2 + ks) * 64 + lane) * 8];
  __syncthreads();

  float gxq[4];
  {
    int tok = sm.toks[0];
    #pragma unroll
    for (int q = 0; q < 4; ++q) gxq[q] = embW[tok * kGE + wv * 64 + q * 16 + lr];
  }
  float cEq[4] = {0.f, 0.f, 0.f, 0.f};
  unsigned short* eg = (unsigned short*)(out + (size_t)b * (kT * kHD));

  for (int s = 0; s < kS; ++s) {
    const int cb = s & 1, nb = cb ^ 1;
    union { u16x8 u; bf16x8 v; } xa0, xa1;
    xa0.u = *(const u16x8*)&sm.xe[cb][(lane >> 4) << 3];
    xa1.u = *(const u16x8*)&sm.xe[cb][32 + ((lane >> 4) << 3)];
    // prefetch next-token input transforms (cell-major embW)
    float gn[4];
    int tokn = sm.toks[(s + 1 < kS) ? (s + 1) : s];
    #pragma unroll
    for (int q = 0; q < 4; ++q) gn[q] = embW[tokn * kGE + wv * 64 + q * 16 + lr];

    f32x4 z = {0.f, 0.f, 0.f, 0.f};
    #pragma unroll
    for (int q = 0; q < 4; ++q) {
      f32x4 a = __builtin_amdgcn_mfma_f32_16x16x32_bf16(xa0.v, eQ[q][0], z, 0, 0, 0);
      a = __builtin_amdgcn_mfma_f32_16x16x32_bf16(xa1.v, eQ[q][1], a, 0, 0, 0);
      float xg = a[0] + gxq[q];          // D uniform across rows (broadcast A)
      float y = fsig(kk * xg);
      float v = (gate == 2) ? (2.0f * y - 1.0f) : y;
      float q0 = DPPB(v, 0x00), q1 = DPPB(v, 0x55), q2 = DPPB(v, 0xAA), q3 = DPPB(v, 0xFF);
      float cn = q1 * cEq[q] + q0 * q2;
      cEq[q] = cn;
      float h = q3 * ftanh(cn);
      if (gate == 0 && lane < 16) {
        int cell = (wv * 4 + q) * 4 + (lr >> 2);
        unsigned short hb = f2bf(h);
        sm.xe[nb][cell] = hb;
        eg[s * 64 + ((((cell >> 3) ^ (s & 7)) << 3) | (cell & 7))] = hb;
      }
    }
    #pragma unroll
    for (int q = 0; q < 4; ++q) gxq[q] = gn[q];
    __syncthreads();
  }
}

// ---------------------------------------------------------------------------
// decoder: FROZEN at R14 (best known: 2353us, VGPR 108, zero spill).
// ---------------------------------------------------------------------------
struct __align__(16) DSm {
  unsigned short enc[kS * kHE];   // 131072 B swizzled bf16
  float wregL[8 * 64 * 4];        // 8192 B  att_w_W lane fragments
  unsigned short afL[4 * 3 * 64 * 8]; // 12288 B W_af MFMA fragments
  float dbL[kGD];                 // 1056 B  folded dec bias (cell-major)
  float wh64L[kGD];               // 1056 B
  float wh65L[kGD];               // 1056 B
  float absL[64];                 // 256 B
  float aa[64];                   // 256 B
  float beta[32];                 // 128 B  atomic target
  unsigned short xv[2][160];      // 640 B  [unused 32 | h bf16 (66) | pad] x2
  float hh2[2][2];                // h64,h65 f32, double-buffered
};  // ~156 KB

union U8 { u16x8 u; bf16x8 v; };

__global__ __launch_bounds__(512, 2)
void dec_kernel(
    const float* __restrict__ att_w_b,
    const unsigned short* __restrict__ decF, const unsigned short* __restrict__ afF,
    const float* __restrict__ wregF_ws, const float* __restrict__ dbias_ws,
    const float* __restrict__ wh64_ws, const float* __restrict__ wh65_ws,
    const float* __restrict__ abias_ws, const float* __restrict__ ainit_ws,
    float* __restrict__ out) {
  __shared__ DSm sm;
  const int b = blockIdx.x, t = threadIdx.x, lane = t & 63, wv = t >> 6;
  const int lr = lane & 15, g = lane >> 4;

  // ---- staging
  {
    const u16x8* src = (const u16x8*)(out + (size_t)b * (kT * kHD));
    u16x8* dst = (u16x8*)sm.enc;
    #pragma unroll
    for (int i = 0; i < 16; ++i) dst[t + i * 512] = src[t + i * 512];
  }
  ((f32x4*)sm.wregL)[t] = ((const f32x4*)wregF_ws)[t];
  for (int i = t; i < 768; i += 512) ((u16x8*)sm.afL)[i] = ((const u16x8*)afF)[i];
  for (int i = t; i < kGD; i += 512) {
    sm.dbL[i] = dbias_ws[i];
    sm.wh64L[i] = wh64_ws[i];
    sm.wh65L[i] = wh65_ws[i];
  }
  if (t < 64) { sm.absL[t] = abias_ws[t]; sm.aa[t] = ainit_ws[t]; }
  if (t < 32) sm.beta[t] = 0.f;
  for (int i = t; i < 320; i += 512) ((unsigned short*)sm.xv)[i] = 0;
  if (t < 4) ((float*)sm.hh2)[t] = 0.f;

  f32x4 wb0, wb1;                 // att_w_b as MFMA C-init
  #pragma unroll
  for (int r = 0; r < 4; ++r) {
    wb0[r] = att_w_b[g * 4 + r];
    wb1[r] = att_w_b[16 + g * 4 + r];
  }
  const int sbase = wv * 128;
  const int tileA = wv, tileB = wv + 8;
  const bool has3 = (wv == 7);    // tile 16 (cells 64,65)

  // PERSISTENT gate fragments (loop-invariant; 24 VGPR)
  U8 qa[3], qb[3];
  #pragma unroll
  for (int ks = 0; ks < 3; ++ks) {
    qa[ks].u = *(const u16x8*)&decF[((tileA * 3 + ks) * 64 + lane) * 8];
    qb[ks].u = *(const u16x8*)&decF[((tileB * 3 + ks) * 64 + lane) * 8];
  }
  float cDa = 0.0f, cDb = 0.0f, cDc = 0.0f;  // per-thread cell states
  __syncthreads();

  for (int step = 0; step < kT; ++step) {
    const int cb = step & 1, nb = cb ^ 1;
    U8 qc[3];
    // ======== PHASE 1: attention sweep ========
    {
      const f32x4* aap = (const f32x4*)sm.aa;
      const f32x4* wrl = (const f32x4*)sm.wregL;
      bf16x8 af[2][2];
      #pragma unroll
      for (int kc = 0; kc < 2; ++kc) {
        f32x4 a0v = aap[kc * 8 + g * 2];
        f32x4 a1v = aap[kc * 8 + g * 2 + 1];
        #pragma unroll
        for (int mt = 0; mt < 2; ++mt) {
          f32x4 w0 = wrl[((mt * 2 + kc) * 2 + 0) * 64 + lane];
          f32x4 w1 = wrl[((mt * 2 + kc) * 2 + 1) * 64 + lane];
          union { bf16x8 v; __hip_bfloat162 h2[4]; } tmp;
          tmp.h2[0] = __float22bfloat162_rn(make_float2(w0.x * a0v.x, w0.y * a0v.y));
          tmp.h2[1] = __float22bfloat162_rn(make_float2(w0.z * a0v.z, w0.w * a0v.w));
          tmp.h2[2] = __float22bfloat162_rn(make_float2(w1.x * a1v.x, w1.y * a1v.y));
          tmp.h2[3] = __float22bfloat162_rn(make_float2(w1.z * a1v.z, w1.w * a1v.w));
          af[mt][kc] = tmp.v;
        }
      }
      float betaAcc[2][4] = {};
      float amax = 0.0f;
      #pragma unroll
      for (int nt = 0; nt < 8; ++nt) {
        int s = sbase + nt * 16 + lr;
        int sw = s & 7;
        U8 e0, e1;
        e0.u = *(const u16x8*)&sm.enc[s * kHE + ((g ^ sw) << 3)];
        e1.u = *(const u16x8*)&sm.enc[s * kHE + (((4 + g) ^ sw) << 3)];
        f32x4 acc0 = __builtin_amdgcn_mfma_f32_16x16x32_bf16(af[0][0], e0.v, wb0, 0, 0, 0);
        acc0 = __builtin_amdgcn_mfma_f32_16x16x32_bf16(af[0][1], e1.v, acc0, 0, 0, 0);
        f32x4 acc1 = __builtin_amdgcn_mfma_f32_16x16x32_bf16(af[1][0], e0.v, wb1, 0, 0, 0);
        acc1 = __builtin_amdgcn_mfma_f32_16x16x32_bf16(af[1][1], e1.v, acc1, 0, 0, 0);
        float u0[4], u1[4], dsum = 0.f;
        #pragma unroll
        for (int r = 0; r < 4; ++r) {
          float x0 = acc0[r], x1 = acc1[r];
          amax = fmaxf(amax, fmaxf(__builtin_fabsf(x0), __builtin_fabsf(x1)));
          u0[r] = fexp2(x0 * __builtin_fmaf(x0 * x0, -0.48089835f, 1.44269504f));
          u1[r] = fexp2(x1 * __builtin_fmaf(x1 * x1, -0.48089835f, 1.44269504f));
          dsum += u0[r] + u1[r];
        }
        dsum += __shfl_xor(dsum, 16);
        dsum += __shfl_xor(dsum, 32);
        float invd = rcp_(dsum);
        #pragma unroll
        for (int r = 0; r < 4; ++r) {
          betaAcc[0][r] += u0[r] * invd;
          betaAcc[1][r] += u1[r] * invd;
        }
      }
      if (__builtin_expect(__any(amax > 0.35f), 0)) {
        #pragma unroll
        for (int mt = 0; mt < 2; ++mt)
          #pragma unroll
          for (int r = 0; r < 4; ++r) betaAcc[mt][r] = 0.f;
        for (int nt = 0; nt < 8; ++nt) {
          int s = sbase + nt * 16 + lr;
          int sw = s & 7;
          U8 e0, e1;
          e0.u = *(const u16x8*)&sm.enc[s * kHE + ((g ^ sw) << 3)];
          e1.u = *(const u16x8*)&sm.enc[s * kHE + (((4 + g) ^ sw) << 3)];
          f32x4 acc0 = __builtin_amdgcn_mfma_f32_16x16x32_bf16(af[0][0], e0.v, wb0, 0, 0, 0);
          acc0 = __builtin_amdgcn_mfma_f32_16x16x32_bf16(af[0][1], e1.v, acc0, 0, 0, 0);
          f32x4 acc1 = __builtin_amdgcn_mfma_f32_16x16x32_bf16(af[1][0], e0.v, wb1, 0, 0, 0);
          acc1 = __builtin_amdgcn_mfma_f32_16x16x32_bf16(af[1][1], e1.v, acc1, 0, 0, 0);
          float u0[4], u1[4], dsum = 0.f;
          for (int r = 0; r < 4; ++r) {
            u0[r] = __expf(tanhf(acc0[r]));
            u1[r] = __expf(tanhf(acc1[r]));
            dsum += u0[r] + u1[r];
          }
          dsum += __shfl_xor(dsum, 16);
          dsum += __shfl_xor(dsum, 32);
          float invd = rcp_(dsum);
          for (int r = 0; r < 4; ++r) {
            betaAcc[0][r] += u0[r] * invd;
            betaAcc[1][r] += u1[r] * invd;
          }
        }
      }
      // wave 7 only: per-step tile-16 fragment load (L2-hot)
      if (has3) {
        const unsigned short* dFp = launder_us(decF);
        #pragma unroll
        for (int ks = 0; ks < 3; ++ks)
          qc[ks].u = *(const u16x8*)&dFp[((16 * 3 + ks) * 64 + lane) * 8];
      }
      // DPP row-reduce + atomic accumulate beta partials
      #pragma unroll
      for (int mt = 0; mt < 2; ++mt)
        #pragma unroll
        for (int r = 0; r < 4; ++r) {
          float v = dpp_red16(betaAcc[mt][r]);
          if (lr == 0) atomicAdd(&sm.beta[mt * 16 + g * 4 + r], v);
        }
    }
    __syncthreads();   // B1
    // ======== PHASE 2: gates + IN-WAVE cells (cell-major tiles) ========
    {
      const f32x4* pb = (const f32x4*)sm.beta;
      f32x4 b0 = pb[g * 2], b1 = pb[g * 2 + 1];
      union { bf16x8 v; __hip_bfloat162 h2[4]; } bfr;
      bfr.h2[0] = __float22bfloat162_rn(make_float2(b0.x - 32.f, b0.y - 32.f));
      bfr.h2[1] = __float22bfloat162_rn(make_float2(b0.z - 32.f, b0.w - 32.f));
      bfr.h2[2] = __float22bfloat162_rn(make_float2(b1.x - 32.f, b1.y - 32.f));
      bfr.h2[3] = __float22bfloat162_rn(make_float2(b1.z - 32.f, b1.w - 32.f));
      U8 xg1, xg2;
      xg1.u = *(const u16x8*)&sm.xv[cb][32 + (g << 3)];
      xg2.u = *(const u16x8*)&sm.xv[cb][64 + (g << 3)];
      float hh0 = sm.hh2[cb][0], hh1 = sm.hh2[cb][1];
      float* op = out + ((size_t)b * kT + step) * kHD;
      const int gate = lane & 3;
      const float kk = (gate == 2) ? 2.0f : 1.0f;
      f32x4 z = {0.f, 0.f, 0.f, 0.f};
      // tileA
      {
        f32x4 ga = __builtin_amdgcn_mfma_f32_16x16x32_bf16(bfr.v, qa[0].v, z, 0, 0, 0);
        ga = __builtin_amdgcn_mfma_f32_16x16x32_bf16(xg1.v, qa[1].v, ga, 0, 0, 0);
        ga = __builtin_amdgcn_mfma_f32_16x16x32_bf16(xg2.v, qa[2].v, ga, 0, 0, 0);
        int jp = tileA * 16 + lr;
        float xg = ga[0] + sm.dbL[jp] + sm.wh64L[jp] * hh0 + sm.wh65L[jp] * hh1;
        float y = fsig(kk * xg);
        float v = (gate == 2) ? (2.0f * y - 1.0f) : y;
        float q0 = DPPB(v, 0x00), q1 = DPPB(v, 0x55), q2 = DPPB(v, 0xAA), q3 = DPPB(v, 0xFF);
        float cn = q1 * cDa + q0 * q2;
        cDa = cn;
        float h = q3 * ftanh(cn);
        if (gate == 0 && lane < 16) {
          int cell = jp >> 2;
          sm.xv[nb][32 + cell] = f2bf(h);
          op[cell] = h;
        }
      }
      // tileB
      {
        f32x4 gb = __builtin_amdgcn_mfma_f32_16x16x32_bf16(bfr.v, qb[0].v, z, 0, 0, 0);
        gb = __builtin_amdgcn_mfma_f32_16x16x32_bf16(xg1.v, qb[1].v, gb, 0, 0, 0);
        gb = __builtin_amdgcn_mfma_f32_16x16x32_bf16(xg2.v, qb[2].v, gb, 0, 0, 0);
        int jp = tileB * 16 + lr;
        float xg = gb[0] + sm.dbL[jp] + sm.wh64L[jp] * hh0 + sm.wh65L[jp] * hh1;
        float y = fsig(kk * xg);
        float v = (gate == 2) ? (2.0f * y - 1.0f) : y;
        float q0 = DPPB(v, 0x00), q1 = DPPB(v, 0x55), q2 = DPPB(v, 0xAA), q3 = DPPB(v, 0xFF);
        float cn = q1 * cDb + q0 * q2;
        cDb = cn;
        float h = q3 * ftanh(cn);
        if (gate == 0 && lane < 16) {
          int cell = jp >> 2;
          sm.xv[nb][32 + cell] = f2bf(h);
          op[cell] = h;
        }
      }
      // tile16 (wave7): cells 64,65 in lanes 0..7
      if (has3) {
        f32x4 gc = __builtin_amdgcn_mfma_f32_16x16x32_bf16(bfr.v, qc[0].v, z, 0, 0, 0);
        gc = __builtin_amdgcn_mfma_f32_16x16x32_bf16(xg1.v, qc[1].v, gc, 0, 0, 0);
        gc = __builtin_amdgcn_mfma_f32_16x16x32_bf16(xg2.v, qc[2].v, gc, 0, 0, 0);
        int jp = 256 + (lane & 7);
        float xg = gc[0] + sm.dbL[jp] + sm.wh64L[jp] * hh0 + sm.wh65L[jp] * hh1;
        float y = fsig(kk * xg);
        float v = (gate == 2) ? (2.0f * y - 1.0f) : y;
        float q0 = DPPB(v, 0x00), q1 = DPPB(v, 0x55), q2 = DPPB(v, 0xAA), q3 = DPPB(v, 0xFF);
        float cn = q1 * cDc + q0 * q2;
        cDc = cn;
        float h = q3 * ftanh(cn);
        if (gate == 0 && lane < 8) {
          int cell = 64 + (lane >> 2);
          sm.xv[nb][32 + cell] = f2bf(h);
          sm.hh2[nb][lane >> 2] = h;
          op[cell] = h;
        }
      }
    }
    __syncthreads();   // B2
    // ======== PHASE 3 (wave 0 only): a-update + beta reset ========
    if (wv == 0) {
      U8 y0, y1, y2;
      y0.u = *(const u16x8*)&sm.xv[nb][32 + (g << 3)];
      y1.u = *(const u16x8*)&sm.xv[nb][64 + (g << 3)];
      y2.u = *(const u16x8*)&sm.xv[nb][96 + (g << 3)];
      f32x4 z = {0.f, 0.f, 0.f, 0.f};
      #pragma unroll
      for (int tt = 0; tt < 4; ++tt) {
        U8 f0, f1, f2;
        f0.u = *(const u16x8*)&sm.afL[((tt * 3 + 0) * 64 + lane) * 8];
        f1.u = *(const u16x8*)&sm.afL[((tt * 3 + 1) * 64 + lane) * 8];
        f2.u = *(const u16x8*)&sm.afL[((tt * 3 + 2) * 64 + lane) * 8];
        f32x4 acc = __builtin_amdgcn_mfma_f32_16x16x32_bf16(y0.v, f0.v, z, 0, 0, 0);
        acc = __builtin_amdgcn_mfma_f32_16x16x32_bf16(y1.v, f1.v, acc, 0, 0, 0);
        acc = __builtin_amdgcn_mfma_f32_16x16x32_bf16(y2.v, f2.v, acc, 0, 0, 0);
        if (lane < 16) sm.aa[tt * 16 + lane] = acc[0] + sm.absL[tt * 16 + lane];
      }
      if (lane < 32) sm.beta[lane] = 0.f;
    }
    __syncthreads();   // B3
  }
}

extern "C" void kernel_launch(void* const* d_in, const int* in_sizes, int n_in,
                              void* d_out, int out_size, void* d_ws, size_t ws_size,
                              hipStream_t stream) {
  const int*   x        = (const int*)d_in[0];
  const float* emb      = (const float*)d_in[2];
  const float* enc_Wih  = (const float*)d_in[3];
  const float* enc_Whh  = (const float*)d_in[4];
  const float* enc_b    = (const float*)d_in[5];
  const float* att_fc_W = (const float*)d_in[6];
  const float* att_fc_b = (const float*)d_in[7];
  const float* att_w_W  = (const float*)d_in[8];
  const float* att_w_b  = (const float*)d_in[9];
  const float* dec_Wih  = (const float*)d_in[10];
  const float* dec_Whh  = (const float*)d_in[11];
  const float* dec_b    = (const float*)d_in[12];
  const float* fin_W    = (const float*)d_in[13];
  const float* fin_b    = (const float*)d_in[14];
  float* out = (float*)d_out;

  float* embW = (float*)d_ws;                                // 256000 f32
  unsigned short* decF = (unsigned short*)(embW + kV * kGE); // 26112 u16
  unsigned short* encF = decF + 17 * 3 * 64 * 8;             // 16384 u16
  unsigned short* afF  = encF + 16 * 2 * 64 * 8;             // 6144 u16
  float* wregF = (float*)(afF + 4 * 3 * 64 * 8);             // 2048 f32
  float* dbias = wregF + 8 * 64 * 4;                         // 264
  float* wh64  = dbias + kGD;                                // 264
  float* wh65  = wh64 + kGD;                                 // 264
  float* abias = wh65 + kGD;                                 // 64
  float* ainit = abias + kHE;                                // 64

  prep_kernel<<<dim3(kV + 6), dim3(256), 0, stream>>>(
      emb, enc_Wih, enc_b, enc_Whh, att_fc_W, att_fc_b, att_w_W, fin_W, fin_b,
      dec_Wih, dec_Whh, dec_b, embW, decF, encF, afF, wregF, dbias, wh64, wh65,
      abias, ainit);
  enc_kernel<<<dim3(kB), dim3(256), 0, stream>>>(x, embW, encF, out);
  dec_kernel<<<dim3(kB), dim3(512), 0, stream>>>(
      att_w_b, decF, afF, wregF, dbias, wh64, wh65, abias, ainit, out);
}

// Round 16
// 2822.245 us; speedup vs baseline: 1.0431x; 1.0431x over previous
//
#include <hip/hip_runtime.h>
#include <hip/hip_bf16.h>

#define kB 128
#define kS 1024
#define kT 512
#define kV 1000
#define kE 128
#define kHE 64
#define kHD 66
#define kATT 32
#define kGE 256   // 4*kHE
#define kGD 264   // 4*kHD

typedef __attribute__((ext_vector_type(4))) float f32x4;
typedef __attribute__((ext_vector_type(8))) short bf16x8;
typedef __attribute__((ext_vector_type(8))) unsigned short u16x8;

__device__ __forceinline__ unsigned short f2bf(float f) {
  unsigned int u = __builtin_bit_cast(unsigned int, f);
  u += 0x7FFFu + ((u >> 16) & 1u);
  return (unsigned short)(u >> 16);
}
__device__ __forceinline__ float rcp_(float x) { return __builtin_amdgcn_rcpf(x); }
__device__ __forceinline__ float fsig(float x)  { return rcp_(1.0f + __expf(-x)); }
__device__ __forceinline__ float ftanh(float x) { return 1.0f - 2.0f * rcp_(1.0f + __expf(2.0f * x)); }
__device__ __forceinline__ float fexp2(float z) {
#if __has_builtin(__builtin_amdgcn_exp2f)
  return __builtin_amdgcn_exp2f(z);
#else
  return __expf(z * 0.6931471805599453f);
#endif
}
__device__ __forceinline__ const unsigned short* launder_us(const unsigned short* p) {
  asm volatile("" : "+s"(p));
  return p;
}
// VALU-rate sum over each contiguous 16-lane row.
__device__ __forceinline__ float dpp_red16(float v) {
  int x = __builtin_bit_cast(int, v);
  v += __builtin_bit_cast(float, __builtin_amdgcn_update_dpp(0, x, 0xB1, 0xf, 0xf, true));  // quad_perm [1,0,3,2]
  x = __builtin_bit_cast(int, v);
  v += __builtin_bit_cast(float, __builtin_amdgcn_update_dpp(0, x, 0x4E, 0xf, 0xf, true));  // quad_perm [2,3,0,1]
  x = __builtin_bit_cast(int, v);
  v += __builtin_bit_cast(float, __builtin_amdgcn_update_dpp(0, x, 0x124, 0xf, 0xf, true)); // row_ror:4
  x = __builtin_bit_cast(int, v);
  v += __builtin_bit_cast(float, __builtin_amdgcn_update_dpp(0, x, 0x128, 0xf, 0xf, true)); // row_ror:8
  return v;
}
// quad_perm broadcast of quad-lane i (ctrl must be a literal)
#define DPPB(v, ctrl) __builtin_bit_cast(float, __builtin_amdgcn_update_dpp(0, __builtin_bit_cast(int, (v)), (ctrl), 0xf, 0xf, true))

// ---------------------------------------------------------------------------
// prep (R11/R14 layout). Fragment layout: frag[((tile*KS + ks)*64 + lane)*8 + jj]
// = B[k][col], col = lane&15. decF cols CELL-MAJOR: j' = cell*4+gate.
// ---------------------------------------------------------------------------
__global__ __launch_bounds__(256) void prep_kernel(
    const float* __restrict__ emb, const float* __restrict__ enc_Wih,
    const float* __restrict__ enc_b, const float* __restrict__ enc_Whh,
    const float* __restrict__ att_fc_W, const float* __restrict__ att_fc_b,
    const float* __restrict__ att_w_W,
    const float* __restrict__ fin_W, const float* __restrict__ fin_b,
    const float* __restrict__ dec_Wih, const float* __restrict__ dec_Whh,
    const float* __restrict__ dec_b,
    float* __restrict__ embW, unsigned short* __restrict__ decF,
    unsigned short* __restrict__ encF, unsigned short* __restrict__ afF,
    float* __restrict__ wregF, float* __restrict__ dbias,
    float* __restrict__ wh64, float* __restrict__ wh65,
    float* __restrict__ abias, float* __restrict__ ainit) {
  int bid = blockIdx.x, tid = threadIdx.x;
  if (bid < kV) {
    float acc = enc_b[tid];
    const float* er = emb + bid * kE;
    const float* wr = enc_Wih + tid * kE;
    for (int e = 0; e < kE; ++e) acc += er[e] * wr[e];
    embW[bid * kGE + tid] = acc;
  } else if (bid == kV) {
    // decF: 17 tiles x 3 ksteps, cols cell-major: j' = cell*4+gate
    for (int i = tid; i < 17 * 3 * 64 * 8; i += 256) {
      int jj = i & 7, lane = (i >> 3) & 63, ts = i >> 9;
      int tile = ts / 3, ks = ts - tile * 3;
      int jp = tile * 16 + (lane & 15);
      int cell = jp >> 2, gate = jp & 3;
      int k = ks * 32 + ((lane >> 4) << 3) + jj;
      float v = 0.f;
      if (cell < kHD) {
        int j = gate * kHD + cell;
        if (k < 32) v = dec_Wih[j * kATT + k];
        else v = dec_Whh[j * kHD + (k - 32)];
      }
      decF[i] = f2bf(v);
    }
  } else if (bid == kV + 1) {
    for (int i = tid; i < 16 * 2 * 64 * 8; i += 256) {
      int jj = i & 7, lane = (i >> 3) & 63, ts = i >> 9;
      int tile = ts >> 1, ks = ts & 1;
      int j = tile * 16 + (lane & 15);
      int k = ks * 32 + ((lane >> 4) << 3) + jj;
      encF[i] = f2bf(enc_Whh[j * kHE + k]);
    }
  } else if (bid == kV + 2) {
    for (int i = tid; i < 4 * 3 * 64 * 8; i += 256) {
      int jj = i & 7, lane = (i >> 3) & 63, ts = i >> 9;
      int tile = ts / 3, ks = ts - tile * 3;
      int aidx = tile * 16 + (lane & 15);
      int m = ks * 32 + ((lane >> 4) << 3) + jj;
      float v = 0.f;
      if (m < kHD)
        for (int e = 0; e < kE; ++e) v += att_fc_W[aidx * kE + e] * fin_W[e * kHD + m];
      afF[i] = f2bf(v);
    }
  } else if (bid == kV + 3) {
    for (int i = tid; i < 8 * 64 * 4; i += 256) {
      int c = i & 3, lane = (i >> 2) & 63, jq = i >> 8;
      int half = jq & 1, kc = (jq >> 1) & 1, mt = jq >> 2;
      wregF[i] = att_w_W[(mt * 16 + (lane & 15)) * kHE + kc * 32 + ((lane >> 4) << 3) + half * 4 + c];
    }
  } else if (bid == kV + 4) {
    // permuted bias / rank-2 fixup arrays: index jp = cell*4+gate
    for (int jp = tid; jp < kGD; jp += 256) {
      int cell = jp >> 2, gate = jp & 3;
      int j = gate * kHD + cell;
      float s = 0.f;
      for (int m = 0; m < kATT; ++m) s += dec_Wih[j * kATT + m];
      dbias[jp] = dec_b[j] + 32.0f * s;
      wh64[jp] = dec_Whh[j * kHD + 64];
      wh65[jp] = dec_Whh[j * kHD + 65];
    }
  } else {
    if (tid < kHE) {
      float acc = att_fc_b[tid];
      for (int e = 0; e < kE; ++e) acc += att_fc_W[tid * kE + e] * fin_b[e];
      abias[tid] = acc;
    } else if (tid < 2 * kHE) {
      int a = tid - kHE;
      float acc = att_fc_b[a];
      for (int e = 0; e < kE; ++e) acc += emb[e] * att_fc_W[a * kE + e];
      ainit[a] = acc;
    }
  }
}

// ---------------------------------------------------------------------------
// encoder: R6-style (best measured: 1 block/b, 256 thr, 2 barriers/step).
// R15's cell-major+DPP rewrite was SLOWER (+120us): its 4 serial
// {MFMA->DPP->exp} chains per wave cost more than the 2 barriers saved.
// ---------------------------------------------------------------------------
__global__ __launch_bounds__(256)
__attribute__((amdgpu_waves_per_eu(1, 1)))
void enc_kernel(
    const int* __restrict__ x, const float* __restrict__ embW,
    const unsigned short* __restrict__ encF, float* __restrict__ out) {
  __shared__ struct __align__(16) {
    unsigned short xe[64];
    float gbuf[kGE];
    int toks[kS];
  } sm;
  const int b = blockIdx.x, t = threadIdx.x, lane = t & 63, wv = t >> 6;

  for (int i = t; i < kS; i += 256) sm.toks[i] = x[b * kS + i];
  if (t < 64) sm.xe[t] = 0;

  u16x8 eQ[4][2];
  #pragma unroll
  for (int q = 0; q < 4; ++q)
    #pragma unroll
    for (int ks = 0; ks < 2; ++ks)
      eQ[q][ks] = *(const u16x8*)&encF[(((wv * 4 + q) * 2 + ks) * 64 + lane) * 8];
  __syncthreads();

  float gx0 = 0, gx1 = 0, gx2 = 0, gx3 = 0;
  if (lane < 16) {
    int tok = sm.toks[0];
    gx0 = embW[tok * kGE + wv * 64 + 0 + lane];
    gx1 = embW[tok * kGE + wv * 64 + 16 + lane];
    gx2 = embW[tok * kGE + wv * 64 + 32 + lane];
    gx3 = embW[tok * kGE + wv * 64 + 48 + lane];
  }
  float cE = 0.0f;
  unsigned short* eg = (unsigned short*)(out + (size_t)b * (kT * kHD));

  for (int s = 0; s < kS; ++s) {
    union { u16x8 u; bf16x8 v; } xa0, xa1;
    xa0.u = *(const u16x8*)&sm.xe[(lane >> 4) << 3];
    xa1.u = *(const u16x8*)&sm.xe[32 + ((lane >> 4) << 3)];
    float gn0 = 0, gn1 = 0, gn2 = 0, gn3 = 0;
    int tokn = sm.toks[(s + 1 < kS) ? (s + 1) : s];
    if (lane < 16) {
      gn0 = embW[tokn * kGE + wv * 64 + 0 + lane];
      gn1 = embW[tokn * kGE + wv * 64 + 16 + lane];
      gn2 = embW[tokn * kGE + wv * 64 + 32 + lane];
      gn3 = embW[tokn * kGE + wv * 64 + 48 + lane];
    }
    f32x4 z = {0.f, 0.f, 0.f, 0.f};
    f32x4 a0 = __builtin_amdgcn_mfma_f32_16x16x32_bf16(xa0.v, eQ[0][0], z, 0, 0, 0);
    a0 = __builtin_amdgcn_mfma_f32_16x16x32_bf16(xa1.v, eQ[0][1], a0, 0, 0, 0);
    f32x4 a1 = __builtin_amdgcn_mfma_f32_16x16x32_bf16(xa0.v, eQ[1][0], z, 0, 0, 0);
    a1 = __builtin_amdgcn_mfma_f32_16x16x32_bf16(xa1.v, eQ[1][1], a1, 0, 0, 0);
    f32x4 a2 = __builtin_amdgcn_mfma_f32_16x16x32_bf16(xa0.v, eQ[2][0], z, 0, 0, 0);
    a2 = __builtin_amdgcn_mfma_f32_16x16x32_bf16(xa1.v, eQ[2][1], a2, 0, 0, 0);
    f32x4 a3 = __builtin_amdgcn_mfma_f32_16x16x32_bf16(xa0.v, eQ[3][0], z, 0, 0, 0);
    a3 = __builtin_amdgcn_mfma_f32_16x16x32_bf16(xa1.v, eQ[3][1], a3, 0, 0, 0);
    if (lane < 16) {
      sm.gbuf[wv * 64 + 0 + lane]  = a0[0] + gx0;
      sm.gbuf[wv * 64 + 16 + lane] = a1[0] + gx1;
      sm.gbuf[wv * 64 + 32 + lane] = a2[0] + gx2;
      sm.gbuf[wv * 64 + 48 + lane] = a3[0] + gx3;
    }
    __syncthreads();
    if (t < 64) {
      float gi = sm.gbuf[t], gf = sm.gbuf[64 + t], gg = sm.gbuf[128 + t], go = sm.gbuf[192 + t];
      cE = fsig(gf) * cE + fsig(gi) * ftanh(gg);
      float h = fsig(go) * ftanh(cE);
      unsigned short hb = f2bf(h);
      sm.xe[t] = hb;
      eg[s * 64 + ((((t >> 3) ^ (s & 7)) << 3) | (t & 7))] = hb;
    }
    __syncthreads();
    gx0 = gn0; gx1 = gn1; gx2 = gn2; gx3 = gn3;
  }
}

// ---------------------------------------------------------------------------
// decoder: FROZEN at R14 (best known: ~2353us, VGPR 108, zero spill).
// Latency-bound on the 512-step aa->scores->beta->h->aa dependency cycle:
// HBM 0.14%, MfmaUtil 5.9%, VALUBusy 31%, 0 conflicts, 0 spill; insensitive
// to +-ops (R8/R12), worse with +serial work (R13), ~flat with -loads (R14).
// ---------------------------------------------------------------------------
struct __align__(16) DSm {
  unsigned short enc[kS * kHE];   // 131072 B swizzled bf16
  float wregL[8 * 64 * 4];        // 8192 B  att_w_W lane fragments
  unsigned short afL[4 * 3 * 64 * 8]; // 12288 B W_af MFMA fragments
  float dbL[kGD];                 // 1056 B  folded dec bias (cell-major)
  float wh64L[kGD];               // 1056 B
  float wh65L[kGD];               // 1056 B
  float absL[64];                 // 256 B
  float aa[64];                   // 256 B
  float beta[32];                 // 128 B  atomic target
  unsigned short xv[2][160];      // 640 B  [unused 32 | h bf16 (66) | pad] x2
  float hh2[2][2];                // h64,h65 f32, double-buffered
};  // ~156 KB

union U8 { u16x8 u; bf16x8 v; };

__global__ __launch_bounds__(512, 2)
void dec_kernel(
    const float* __restrict__ att_w_b,
    const unsigned short* __restrict__ decF, const unsigned short* __restrict__ afF,
    const float* __restrict__ wregF_ws, const float* __restrict__ dbias_ws,
    const float* __restrict__ wh64_ws, const float* __restrict__ wh65_ws,
    const float* __restrict__ abias_ws, const float* __restrict__ ainit_ws,
    float* __restrict__ out) {
  __shared__ DSm sm;
  const int b = blockIdx.x, t = threadIdx.x, lane = t & 63, wv = t >> 6;
  const int lr = lane & 15, g = lane >> 4;

  // ---- staging
  {
    const u16x8* src = (const u16x8*)(out + (size_t)b * (kT * kHD));
    u16x8* dst = (u16x8*)sm.enc;
    #pragma unroll
    for (int i = 0; i < 16; ++i) dst[t + i * 512] = src[t + i * 512];
  }
  ((f32x4*)sm.wregL)[t] = ((const f32x4*)wregF_ws)[t];
  for (int i = t; i < 768; i += 512) ((u16x8*)sm.afL)[i] = ((const u16x8*)afF)[i];
  for (int i = t; i < kGD; i += 512) {
    sm.dbL[i] = dbias_ws[i];
    sm.wh64L[i] = wh64_ws[i];
    sm.wh65L[i] = wh65_ws[i];
  }
  if (t < 64) { sm.absL[t] = abias_ws[t]; sm.aa[t] = ainit_ws[t]; }
  if (t < 32) sm.beta[t] = 0.f;
  for (int i = t; i < 320; i += 512) ((unsigned short*)sm.xv)[i] = 0;
  if (t < 4) ((float*)sm.hh2)[t] = 0.f;

  f32x4 wb0, wb1;                 // att_w_b as MFMA C-init
  #pragma unroll
  for (int r = 0; r < 4; ++r) {
    wb0[r] = att_w_b[g * 4 + r];
    wb1[r] = att_w_b[16 + g * 4 + r];
  }
  const int sbase = wv * 128;
  const int tileA = wv, tileB = wv + 8;
  const bool has3 = (wv == 7);    // tile 16 (cells 64,65)

  // PERSISTENT gate fragments (loop-invariant; 24 VGPR)
  U8 qa[3], qb[3];
  #pragma unroll
  for (int ks = 0; ks < 3; ++ks) {
    qa[ks].u = *(const u16x8*)&decF[((tileA * 3 + ks) * 64 + lane) * 8];
    qb[ks].u = *(const u16x8*)&decF[((tileB * 3 + ks) * 64 + lane) * 8];
  }
  float cDa = 0.0f, cDb = 0.0f, cDc = 0.0f;  // per-thread cell states
  __syncthreads();

  for (int step = 0; step < kT; ++step) {
    const int cb = step & 1, nb = cb ^ 1;
    U8 qc[3];
    // ======== PHASE 1: attention sweep ========
    {
      const f32x4* aap = (const f32x4*)sm.aa;
      const f32x4* wrl = (const f32x4*)sm.wregL;
      bf16x8 af[2][2];
      #pragma unroll
      for (int kc = 0; kc < 2; ++kc) {
        f32x4 a0v = aap[kc * 8 + g * 2];
        f32x4 a1v = aap[kc * 8 + g * 2 + 1];
        #pragma unroll
        for (int mt = 0; mt < 2; ++mt) {
          f32x4 w0 = wrl[((mt * 2 + kc) * 2 + 0) * 64 + lane];
          f32x4 w1 = wrl[((mt * 2 + kc) * 2 + 1) * 64 + lane];
          union { bf16x8 v; __hip_bfloat162 h2[4]; } tmp;
          tmp.h2[0] = __float22bfloat162_rn(make_float2(w0.x * a0v.x, w0.y * a0v.y));
          tmp.h2[1] = __float22bfloat162_rn(make_float2(w0.z * a0v.z, w0.w * a0v.w));
          tmp.h2[2] = __float22bfloat162_rn(make_float2(w1.x * a1v.x, w1.y * a1v.y));
          tmp.h2[3] = __float22bfloat162_rn(make_float2(w1.z * a1v.z, w1.w * a1v.w));
          af[mt][kc] = tmp.v;
        }
      }
      float betaAcc[2][4] = {};
      float amax = 0.0f;
      #pragma unroll
      for (int nt = 0; nt < 8; ++nt) {
        int s = sbase + nt * 16 + lr;
        int sw = s & 7;
        U8 e0, e1;
        e0.u = *(const u16x8*)&sm.enc[s * kHE + ((g ^ sw) << 3)];
        e1.u = *(const u16x8*)&sm.enc[s * kHE + (((4 + g) ^ sw) << 3)];
        f32x4 acc0 = __builtin_amdgcn_mfma_f32_16x16x32_bf16(af[0][0], e0.v, wb0, 0, 0, 0);
        acc0 = __builtin_amdgcn_mfma_f32_16x16x32_bf16(af[0][1], e1.v, acc0, 0, 0, 0);
        f32x4 acc1 = __builtin_amdgcn_mfma_f32_16x16x32_bf16(af[1][0], e0.v, wb1, 0, 0, 0);
        acc1 = __builtin_amdgcn_mfma_f32_16x16x32_bf16(af[1][1], e1.v, acc1, 0, 0, 0);
        float u0[4], u1[4], dsum = 0.f;
        #pragma unroll
        for (int r = 0; r < 4; ++r) {
          float x0 = acc0[r], x1 = acc1[r];
          amax = fmaxf(amax, fmaxf(__builtin_fabsf(x0), __builtin_fabsf(x1)));
          u0[r] = fexp2(x0 * __builtin_fmaf(x0 * x0, -0.48089835f, 1.44269504f));
          u1[r] = fexp2(x1 * __builtin_fmaf(x1 * x1, -0.48089835f, 1.44269504f));
          dsum += u0[r] + u1[r];
        }
        dsum += __shfl_xor(dsum, 16);
        dsum += __shfl_xor(dsum, 32);
        float invd = rcp_(dsum);
        #pragma unroll
        for (int r = 0; r < 4; ++r) {
          betaAcc[0][r] += u0[r] * invd;
          betaAcc[1][r] += u1[r] * invd;
        }
      }
      if (__builtin_expect(__any(amax > 0.35f), 0)) {
        #pragma unroll
        for (int mt = 0; mt < 2; ++mt)
          #pragma unroll
          for (int r = 0; r < 4; ++r) betaAcc[mt][r] = 0.f;
        for (int nt = 0; nt < 8; ++nt) {
          int s = sbase + nt * 16 + lr;
          int sw = s & 7;
          U8 e0, e1;
          e0.u = *(const u16x8*)&sm.enc[s * kHE + ((g ^ sw) << 3)];
          e1.u = *(const u16x8*)&sm.enc[s * kHE + (((4 + g) ^ sw) << 3)];
          f32x4 acc0 = __builtin_amdgcn_mfma_f32_16x16x32_bf16(af[0][0], e0.v, wb0, 0, 0, 0);
          acc0 = __builtin_amdgcn_mfma_f32_16x16x32_bf16(af[0][1], e1.v, acc0, 0, 0, 0);
          f32x4 acc1 = __builtin_amdgcn_mfma_f32_16x16x32_bf16(af[1][0], e0.v, wb1, 0, 0, 0);
          acc1 = __builtin_amdgcn_mfma_f32_16x16x32_bf16(af[1][1], e1.v, acc1, 0, 0, 0);
          float u0[4], u1[4], dsum = 0.f;
          for (int r = 0; r < 4; ++r) {
            u0[r] = __expf(tanhf(acc0[r]));
            u1[r] = __expf(tanhf(acc1[r]));
            dsum += u0[r] + u1[r];
          }
          dsum += __shfl_xor(dsum, 16);
          dsum += __shfl_xor(dsum, 32);
          float invd = rcp_(dsum);
          for (int r = 0; r < 4; ++r) {
            betaAcc[0][r] += u0[r] * invd;
            betaAcc[1][r] += u1[r] * invd;
          }
        }
      }
      // wave 7 only: per-step tile-16 fragment load (L2-hot)
      if (has3) {
        const unsigned short* dFp = launder_us(decF);
        #pragma unroll
        for (int ks = 0; ks < 3; ++ks)
          qc[ks].u = *(const u16x8*)&dFp[((16 * 3 + ks) * 64 + lane) * 8];
      }
      // DPP row-reduce + atomic accumulate beta partials
      #pragma unroll
      for (int mt = 0; mt < 2; ++mt)
        #pragma unroll
        for (int r = 0; r < 4; ++r) {
          float v = dpp_red16(betaAcc[mt][r]);
          if (lr == 0) atomicAdd(&sm.beta[mt * 16 + g * 4 + r], v);
        }
    }
    __syncthreads();   // B1
    // ======== PHASE 2: gates + IN-WAVE cells (cell-major tiles) ========
    {
      const f32x4* pb = (const f32x4*)sm.beta;
      f32x4 b0 = pb[g * 2], b1 = pb[g * 2 + 1];
      union { bf16x8 v; __hip_bfloat162 h2[4]; } bfr;
      bfr.h2[0] = __float22bfloat162_rn(make_float2(b0.x - 32.f, b0.y - 32.f));
      bfr.h2[1] = __float22bfloat162_rn(make_float2(b0.z - 32.f, b0.w - 32.f));
      bfr.h2[2] = __float22bfloat162_rn(make_float2(b1.x - 32.f, b1.y - 32.f));
      bfr.h2[3] = __float22bfloat162_rn(make_float2(b1.z - 32.f, b1.w - 32.f));
      U8 xg1, xg2;
      xg1.u = *(const u16x8*)&sm.xv[cb][32 + (g << 3)];
      xg2.u = *(const u16x8*)&sm.xv[cb][64 + (g << 3)];
      float hh0 = sm.hh2[cb][0], hh1 = sm.hh2[cb][1];
      float* op = out + ((size_t)b * kT + step) * kHD;
      const int gate = lane & 3;
      const float kk = (gate == 2) ? 2.0f : 1.0f;
      f32x4 z = {0.f, 0.f, 0.f, 0.f};
      // tileA
      {
        f32x4 ga = __builtin_amdgcn_mfma_f32_16x16x32_bf16(bfr.v, qa[0].v, z, 0, 0, 0);
        ga = __builtin_amdgcn_mfma_f32_16x16x32_bf16(xg1.v, qa[1].v, ga, 0, 0, 0);
        ga = __builtin_amdgcn_mfma_f32_16x16x32_bf16(xg2.v, qa[2].v, ga, 0, 0, 0);
        int jp = tileA * 16 + lr;
        float xg = ga[0] + sm.dbL[jp] + sm.wh64L[jp] * hh0 + sm.wh65L[jp] * hh1;
        float y = fsig(kk * xg);
        float v = (gate == 2) ? (2.0f * y - 1.0f) : y;
        float q0 = DPPB(v, 0x00), q1 = DPPB(v, 0x55), q2 = DPPB(v, 0xAA), q3 = DPPB(v, 0xFF);
        float cn = q1 * cDa + q0 * q2;
        cDa = cn;
        float h = q3 * ftanh(cn);
        if (gate == 0 && lane < 16) {
          int cell = jp >> 2;
          sm.xv[nb][32 + cell] = f2bf(h);
          op[cell] = h;
        }
      }
      // tileB
      {
        f32x4 gb = __builtin_amdgcn_mfma_f32_16x16x32_bf16(bfr.v, qb[0].v, z, 0, 0, 0);
        gb = __builtin_amdgcn_mfma_f32_16x16x32_bf16(xg1.v, qb[1].v, gb, 0, 0, 0);
        gb = __builtin_amdgcn_mfma_f32_16x16x32_bf16(xg2.v, qb[2].v, gb, 0, 0, 0);
        int jp = tileB * 16 + lr;
        float xg = gb[0] + sm.dbL[jp] + sm.wh64L[jp] * hh0 + sm.wh65L[jp] * hh1;
        float y = fsig(kk * xg);
        float v = (gate == 2) ? (2.0f * y - 1.0f) : y;
        float q0 = DPPB(v, 0x00), q1 = DPPB(v, 0x55), q2 = DPPB(v, 0xAA), q3 = DPPB(v, 0xFF);
        float cn = q1 * cDb + q0 * q2;
        cDb = cn;
        float h = q3 * ftanh(cn);
        if (gate == 0 && lane < 16) {
          int cell = jp >> 2;
          sm.xv[nb][32 + cell] = f2bf(h);
          op[cell] = h;
        }
      }
      // tile16 (wave7): cells 64,65 in lanes 0..7
      if (has3) {
        f32x4 gc = __builtin_amdgcn_mfma_f32_16x16x32_bf16(bfr.v, qc[0].v, z, 0, 0, 0);
        gc = __builtin_amdgcn_mfma_f32_16x16x32_bf16(xg1.v, qc[1].v, gc, 0, 0, 0);
        gc = __builtin_amdgcn_mfma_f32_16x16x32_bf16(xg2.v, qc[2].v, gc, 0, 0, 0);
        int jp = 256 + (lane & 7);
        float xg = gc[0] + sm.dbL[jp] + sm.wh64L[jp] * hh0 + sm.wh65L[jp] * hh1;
        float y = fsig(kk * xg);
        float v = (gate == 2) ? (2.0f * y - 1.0f) : y;
        float q0 = DPPB(v, 0x00), q1 = DPPB(v, 0x55), q2 = DPPB(v, 0xAA), q3 = DPPB(v, 0xFF);
        float cn = q1 * cDc + q0 * q2;
        cDc = cn;
        float h = q3 * ftanh(cn);
        if (gate == 0 && lane < 8) {
          int cell = 64 + (lane >> 2);
          sm.xv[nb][32 + cell] = f2bf(h);
          sm.hh2[nb][lane >> 2] = h;
          op[cell] = h;
        }
      }
    }
    __syncthreads();   // B2
    // ======== PHASE 3 (wave 0 only): a-update + beta reset ========
    if (wv == 0) {
      U8 y0, y1, y2;
      y0.u = *(const u16x8*)&sm.xv[nb][32 + (g << 3)];
      y1.u = *(const u16x8*)&sm.xv[nb][64 + (g << 3)];
      y2.u = *(const u16x8*)&sm.xv[nb][96 + (g << 3)];
      f32x4 z = {0.f, 0.f, 0.f, 0.f};
      #pragma unroll
      for (int tt = 0; tt < 4; ++tt) {
        U8 f0, f1, f2;
        f0.u = *(const u16x8*)&sm.afL[((tt * 3 + 0) * 64 + lane) * 8];
        f1.u = *(const u16x8*)&sm.afL[((tt * 3 + 1) * 64 + lane) * 8];
        f2.u = *(const u16x8*)&sm.afL[((tt * 3 + 2) * 64 + lane) * 8];
        f32x4 acc = __builtin_amdgcn_mfma_f32_16x16x32_bf16(y0.v, f0.v, z, 0, 0, 0);
        acc = __builtin_amdgcn_mfma_f32_16x16x32_bf16(y1.v, f1.v, acc, 0, 0, 0);
        acc = __builtin_amdgcn_mfma_f32_16x16x32_bf16(y2.v, f2.v, acc, 0, 0, 0);
        if (lane < 16) sm.aa[tt * 16 + lane] = acc[0] + sm.absL[tt * 16 + lane];
      }
      if (lane < 32) sm.beta[lane] = 0.f;
    }
    __syncthreads();   // B3
  }
}

extern "C" void kernel_launch(void* const* d_in, const int* in_sizes, int n_in,
                              void* d_out, int out_size, void* d_ws, size_t ws_size,
                              hipStream_t stream) {
  const int*   x        = (const int*)d_in[0];
  const float* emb      = (const float*)d_in[2];
  const float* enc_Wih  = (const float*)d_in[3];
  const float* enc_Whh  = (const float*)d_in[4];
  const float* enc_b    = (const float*)d_in[5];
  const float* att_fc_W = (const float*)d_in[6];
  const float* att_fc_b = (const float*)d_in[7];
  const float* att_w_W  = (const float*)d_in[8];
  const float* att_w_b  = (const float*)d_in[9];
  const float* dec_Wih  = (const float*)d_in[10];
  const float* dec_Whh  = (const float*)d_in[11];
  const float* dec_b    = (const float*)d_in[12];
  const float* fin_W    = (const float*)d_in[13];
  const float* fin_b    = (const float*)d_in[14];
  float* out = (float*)d_out;

  float* embW = (float*)d_ws;                                // 256000 f32
  unsigned short* decF = (unsigned short*)(embW + kV * kGE); // 26112 u16
  unsigned short* encF = decF + 17 * 3 * 64 * 8;             // 16384 u16
  unsigned short* afF  = encF + 16 * 2 * 64 * 8;             // 6144 u16
  float* wregF = (float*)(afF + 4 * 3 * 64 * 8);             // 2048 f32
  float* dbias = wregF + 8 * 64 * 4;                         // 264
  float* wh64  = dbias + kGD;                                // 264
  float* wh65  = wh64 + kGD;                                 // 264
  float* abias = wh65 + kGD;                                 // 64
  float* ainit = abias + kHE;                                // 64

  prep_kernel<<<dim3(kV + 6), dim3(256), 0, stream>>>(
      emb, enc_Wih, enc_b, enc_Whh, att_fc_W, att_fc_b, att_w_W, fin_W, fin_b,
      dec_Wih, dec_Whh, dec_b, embW, decF, encF, afF, wregF, dbias, wh64, wh65,
      abias, ainit);
  enc_kernel<<<dim3(kB), dim3(256), 0, stream>>>(x, embW, encF, out);
  dec_kernel<<<dim3(kB), dim3(512), 0, stream>>>(
      att_w_b, decF, afF, wregF, dbias, wh64, wh65, abias, ainit, out);
}